// Round 12
// baseline (178.110 us; speedup 1.0000x reference)
//
#include <hip/hip_runtime.h>
#include <math.h>

static constexpr int Dh = 128;
static constexpr int NH = 4;
static constexpr int NB = 16;
static constexpr int SS = 1024;
static constexpr float NEGF = -1e9f;
static constexpr float SCALE = 0.08838834764831843f;  // 1/sqrt(128)

typedef short s16x8 __attribute__((ext_vector_type(8)));
typedef short s16x4 __attribute__((ext_vector_type(4)));
typedef float f32x4 __attribute__((ext_vector_type(4)));

#define MFMA32(a, b, c) __builtin_amdgcn_mfma_f32_16x16x32_bf16(a, b, c, 0, 0, 0)
// K=16 bf16 MFMA: layouts HW-validated (byte-identical absmax across rounds).
#define MFMA16(a, b, c) __builtin_amdgcn_mfma_f32_16x16x16bf16_1k(a, b, c, 0, 0, 0)

// async global->LDS, 16B per lane; LDS dest is wave-uniform base + lane*16 (linear),
// per-lane GLOBAL address carries the swizzle (m173 pattern, HW-validated in R10).
#define GL2LDS16(g, l)                                                                   \
    __builtin_amdgcn_global_load_lds((const __attribute__((address_space(1))) void*)(g), \
                                     (__attribute__((address_space(3))) void*)(l), 16, 0, 0)

__device__ inline ushort f2bf(float f) {
    union { float f; unsigned u; } v; v.f = f;
    unsigned r = v.u + 0x7FFFu + ((v.u >> 16) & 1u);
    return (ushort)(r >> 16);
}

// ---------------- K0: LN partial sums + bit-mask prep + W_in bf16 pre-convert ----------------
__global__ __launch_bounds__(256) void ln_mask_kernel(const float* __restrict__ x,
                                                      float* __restrict__ part,
                                                      const int* __restrict__ edge,
                                                      unsigned long long* __restrict__ mbit,
                                                      const float* __restrict__ w_in,
                                                      ushort* __restrict__ wb) {
    const int b = blockIdx.x >> 4, p = blockIdx.x & 15;
    const int tid = threadIdx.x;
    const float4* xb4 = (const float4*)(x + (size_t)b * SS * Dh) + p * 2048;
    float s = 0.f, ss = 0.f;
    for (int i = tid; i < 2048; i += 256) {
        float4 v = xb4[i];
        s  += v.x + v.y + v.z + v.w;
        ss += v.x * v.x + v.y * v.y + v.z * v.z + v.w * v.w;
    }
    __shared__ float r1[256], r2[256];
    r1[tid] = s; r2[tid] = ss;
    __syncthreads();
    for (int off = 128; off > 0; off >>= 1) {
        if (tid < off) { r1[tid] += r1[tid + off]; r2[tid] += r2[tid + off]; }
        __syncthreads();
    }
    if (tid == 0) { part[blockIdx.x * 2] = r1[0]; part[blockIdx.x * 2 + 1] = r2[0]; }

    if (blockIdx.x < 64) {
        const int idx = blockIdx.x * 256 + tid;   // < 1024*16
        const int sr = idx >> 4, w = idx & 15;
        const int4* ep = (const int4*)(edge + (size_t)sr * SS + w * 64);
        unsigned long long m0 = 0, m1 = 0, m2 = 0, m3 = 0;
        #pragma unroll
        for (int j = 0; j < 16; ++j) {
            int4 e = ep[j];
            const int base = j * 4;
            m0 |= (e.x == 1) ? (1ull << (base + 0)) : 0ull;
            m1 |= (e.x == 2) ? (1ull << (base + 0)) : 0ull;
            m2 |= (e.x == 3) ? (1ull << (base + 0)) : 0ull;
            m3 |= (e.x == 4) ? (1ull << (base + 0)) : 0ull;
            m0 |= (e.y == 1) ? (1ull << (base + 1)) : 0ull;
            m1 |= (e.y == 2) ? (1ull << (base + 1)) : 0ull;
            m2 |= (e.y == 3) ? (1ull << (base + 1)) : 0ull;
            m3 |= (e.y == 4) ? (1ull << (base + 1)) : 0ull;
            m0 |= (e.z == 1) ? (1ull << (base + 2)) : 0ull;
            m1 |= (e.z == 2) ? (1ull << (base + 2)) : 0ull;
            m2 |= (e.z == 3) ? (1ull << (base + 2)) : 0ull;
            m3 |= (e.z == 4) ? (1ull << (base + 2)) : 0ull;
            m0 |= (e.w == 1) ? (1ull << (base + 3)) : 0ull;
            m1 |= (e.w == 2) ? (1ull << (base + 3)) : 0ull;
            m2 |= (e.w == 3) ? (1ull << (base + 3)) : 0ull;
            m3 |= (e.w == 4) ? (1ull << (base + 3)) : 0ull;
        }
        mbit[((size_t)0 * SS + sr) * 16 + w] = m0;
        mbit[((size_t)1 * SS + sr) * 16 + w] = m1;
        mbit[((size_t)2 * SS + sr) * 16 + w] = m2;
        mbit[((size_t)3 * SS + sr) * 16 + w] = m3;
    } else if (blockIdx.x < 160) {
        // W_in -> bf16 : 1536*128 elems; 96 blocks x 256 threads x 8
        const int slot = (blockIdx.x - 64) * 256 + tid;
        const float4* sp = (const float4*)w_in + (size_t)slot * 2;
        float4 a = sp[0], c = sp[1];
        s16x8 pk;
        pk[0] = (short)f2bf(a.x); pk[1] = (short)f2bf(a.y);
        pk[2] = (short)f2bf(a.z); pk[3] = (short)f2bf(a.w);
        pk[4] = (short)f2bf(c.x); pk[5] = (short)f2bf(c.y);
        pk[6] = (short)f2bf(c.z); pk[7] = (short)f2bf(c.w);
        *(s16x8*)(wb + (size_t)slot * 8) = pk;
    }
}

// ---------------- K1: QKV projection, barrier-free main loop.
// Intra-block operand reuse is near-zero (A rows are wave-exclusive; B is L2-served), so
// fragments are read DIRECTLY from global: A from x (f32) with LN fused inline (mu/rstd
// from part), B from pre-converted bf16 wb. No main-loop LDS, no barriers; each operand
// byte read once per block; 1536 blocks provide the TLP. Epilogue Rs unchanged. ----------------
__global__ __launch_bounds__(256) void qkv_mfma_kernel(const float* __restrict__ x,    // [16384][128] f32
                                                       const float* __restrict__ part, // [256][2]
                                                       const ushort* __restrict__ wb,  // [1536][128] bf16
                                                       const float* __restrict__ bias, // [1536]
                                                       ushort* __restrict__ qo,
                                                       ushort* __restrict__ ko,
                                                       ushort* __restrict__ vto) {
    __shared__ ushort Rs[128 * 136];          // epilogue-only LDS (34.8 KB)
    const int tid = threadIdx.x, wave = tid >> 6, lane = tid & 63;
    const int lrow = lane & 15, quad = lane >> 4;
    const int wm = wave & 1, wn = wave >> 1;
    const int col0 = blockIdx.x * 128;
    const int row0 = blockIdx.y * 128;
    const int bb = row0 >> 10;

    float s_ = 0.f, ss_ = 0.f;
    #pragma unroll
    for (int p = 0; p < 16; ++p) { s_ += part[(bb * 16 + p) * 2]; ss_ += part[(bb * 16 + p) * 2 + 1]; }
    const float invN = 1.0f / (float)(SS * Dh);
    const float mu = s_ * invN;
    const float rstd = 1.0f / sqrtf(ss_ * invN - mu * mu + 1e-5f);

    f32x4 acc[4][4];
    #pragma unroll
    for (int mi = 0; mi < 4; ++mi)
        #pragma unroll
        for (int ni = 0; ni < 4; ++ni) acc[mi][ni] = (f32x4){0.f, 0.f, 0.f, 0.f};

    #pragma unroll
    for (int kc = 0; kc < 4; ++kc) {
        s16x8 af[4], bf[4];
        #pragma unroll
        for (int mi = 0; mi < 4; ++mi) {
            const float* ap = x + (size_t)(row0 + wm * 64 + 16 * mi + lrow) * Dh + kc * 32 + quad * 8;
            float4 a0 = *(const float4*)ap;
            float4 a1 = *(const float4*)(ap + 4);
            s16x8 pa;
            pa[0] = (short)f2bf((a0.x - mu) * rstd); pa[1] = (short)f2bf((a0.y - mu) * rstd);
            pa[2] = (short)f2bf((a0.z - mu) * rstd); pa[3] = (short)f2bf((a0.w - mu) * rstd);
            pa[4] = (short)f2bf((a1.x - mu) * rstd); pa[5] = (short)f2bf((a1.y - mu) * rstd);
            pa[6] = (short)f2bf((a1.z - mu) * rstd); pa[7] = (short)f2bf((a1.w - mu) * rstd);
            af[mi] = pa;
        }
        #pragma unroll
        for (int ni = 0; ni < 4; ++ni)
            bf[ni] = *(const s16x8*)(wb + (size_t)(col0 + wn * 64 + 16 * ni + lrow) * Dh + kc * 32 + quad * 8);
        #pragma unroll
        for (int mi = 0; mi < 4; ++mi)
            #pragma unroll
            for (int ni = 0; ni < 4; ++ni)
                acc[mi][ni] = MFMA32(af[mi], bf[ni], acc[mi][ni]);
    }

    const int seg = col0 % 384, typ = seg >> 7, h = col0 / 384;
    const size_t bh = (size_t)bb * NH + h;
    const int sl_blk = row0 & 1023;
    float bia[4];
    #pragma unroll
    for (int ni = 0; ni < 4; ++ni) bia[ni] = bias[col0 + wn * 64 + 16 * ni + lrow];
    const float sc = (typ == 0) ? SCALE : 1.f;

    if (typ < 2) {
        #pragma unroll
        for (int mi = 0; mi < 4; ++mi)
            #pragma unroll
            for (int ni = 0; ni < 4; ++ni)
                #pragma unroll
                for (int reg = 0; reg < 4; ++reg)
                    Rs[(wm * 64 + 16 * mi + quad * 4 + reg) * 136 + wn * 64 + 16 * ni + lrow]
                        = f2bf((acc[mi][ni][reg] + bia[ni]) * sc);
    } else {
        #pragma unroll
        for (int mi = 0; mi < 4; ++mi)
            #pragma unroll
            for (int ni = 0; ni < 4; ++ni) {
                ushort4 pk;
                pk.x = f2bf(acc[mi][ni][0] + bia[ni]);
                pk.y = f2bf(acc[mi][ni][1] + bia[ni]);
                pk.z = f2bf(acc[mi][ni][2] + bia[ni]);
                pk.w = f2bf(acc[mi][ni][3] + bia[ni]);
                *(ushort4*)&Rs[(wn * 64 + 16 * ni + lrow) * 136 + wm * 64 + 16 * mi + quad * 4] = pk;
            }
    }
    __syncthreads();

    ushort* dstb;
    int pitch;
    if (typ == 0)      { dstb = qo  + bh * SS * 128 + (size_t)sl_blk * 128; pitch = 128; }
    else if (typ == 1) { dstb = ko  + bh * SS * 128 + (size_t)sl_blk * 128; pitch = 128; }
    else               { dstb = vto + bh * (size_t)128 * SS + sl_blk;       pitch = SS;  }
    #pragma unroll
    for (int p = 0; p < 8; ++p) {
        int slot = p * 256 + tid;
        int r = slot >> 4, c8 = (slot & 15) * 8;
        *(s16x8*)&dstb[(size_t)r * pitch + c8] = *(const s16x8*)&Rs[r * 136 + c8];
    }
}

// ---------------- K2: R10/R11 flash attention (async gload_lds staging, best-measured) ----------------
static constexpr int KSW = 128;                      // Ks row stride (linear, content swizzled)
static constexpr int VSW = 64;                       // Vt row stride
static constexpr int TILE_U = 64 * KSW + 128 * VSW;  // 16384 ushorts per buffer
static constexpr int WS_LD = 136;
static constexpr int OS_LD = 136;

__global__ __launch_bounds__(256, 2) void attn_fused_kernel(const ushort* __restrict__ qg_,
                                                            const ushort* __restrict__ kg_,
                                                            const ushort* __restrict__ vg_,
                                                            const unsigned long long* __restrict__ mbit,
                                                            const float* __restrict__ wo,
                                                            const float* __restrict__ bo,
                                                            float* __restrict__ out) {
    // XCD swizzle: blockIdx.x = (b,h) so all 8 q-tiles of a (b,h) share id%8 -> same XCD L2
    const int bhi = blockIdx.x, qt = blockIdx.y;
    const int b = bhi >> 2, h = bhi & 3;
    const int s0 = qt * 128;
    const int tid = threadIdx.x;
    const int wave = tid >> 6, lane = tid & 63;
    const int lrow = lane & 15, quad = lane >> 4;

    __shared__ ushort smem[2 * TILE_U];          // 65536 B exactly
    ushort* Osl = smem + wave * 16 * OS_LD;      // epilogue: per-wave [q][d], aliases buffers
    ushort* Ws  = smem + 4 * 16 * OS_LD;         // epilogue: Wo[h] bf16 [e][d]

    const size_t bh = (size_t)(b * NH + h);
    const ushort* qg = qg_ + bh * SS * 128;
    const ushort* kg = kg_ + bh * SS * 128;
    const ushort* vg = vg_ + bh * 128 * SS;
    const unsigned long long* mrow0 = mbit + ((size_t)h * SS + (s0 + 32 * wave + lrow)) * 16;
    const unsigned long long* mrow1 = mrow0 + 16 * 16;

    // Q fragments (B-operand of S^T MFMA32): n=q=lane&15, k=kc*32+quad*8+j
    s16x8 qf[2][4];
    #pragma unroll
    for (int g = 0; g < 2; ++g) {
        const ushort* qr = qg + (size_t)(s0 + 32 * wave + 16 * g + lrow) * 128 + quad * 8;
        #pragma unroll
        for (int kc = 0; kc < 4; ++kc) qf[g][kc] = *(const s16x8*)(qr + kc * 32);
    }

    // per-lane swizzled source offsets (constant across tiles):
    // K: lds row rk (4 rows/call), chunk (lane&15); src col = ((lane&15)*8) ^ ((rk&7)<<3)
    // V: lds row rv (8 rows/call), chunk (lane&7);  src col = ((lane&7)*8) ^ ((rv&7)<<3)
    #define ISSUE_TILE(T0, KD, VD)                                                            \
        {                                                                                     \
            _Pragma("unroll")                                                                 \
            for (int p = 0; p < 4; ++p) {                                                     \
                const int rk = wave * 16 + p * 4 + (lane >> 4);                               \
                GL2LDS16(kg + (size_t)((T0) + rk) * 128 + (((lane & 15) * 8) ^ ((rk & 7) << 3)), \
                         (KD) + (wave * 16 + p * 4) * KSW);                                   \
                const int rv = wave * 32 + p * 8 + (lane >> 3);                               \
                GL2LDS16(vg + (size_t)rv * SS + (T0) + (((lane & 7) * 8) ^ ((rv & 7) << 3)),  \
                         (VD) + (wave * 32 + p * 8) * VSW);                                   \
            }                                                                                 \
        }

    // prologue: issue tile 0 into buffer 0
    ISSUE_TILE(0, smem, smem + 64 * KSW);

    // O^T accumulators: D[m=d][n=q]: q = lane&15 (aligned with softmax state!), d = 16*nb+quad*4+reg
    f32x4 oacc[2][8];
    #pragma unroll
    for (int g = 0; g < 2; ++g)
        #pragma unroll
        for (int nb = 0; nb < 8; ++nb) oacc[g][nb] = (f32x4){0.f, 0.f, 0.f, 0.f};
    float m_run[2] = {-INFINITY, -INFINITY};
    float l_run[2] = {0.f, 0.f};

    for (int kt = 0; kt < 16; ++kt) {
        const ushort* Ksc = smem + (kt & 1) * TILE_U;
        const ushort* Vtc = Ksc + 64 * KSW;

        __syncthreads();   // drains vmcnt: tile kt resident in buf[kt&1]; all waves aligned

        if (kt < 15) {
            ushort* Ksn = smem + ((kt + 1) & 1) * TILE_U;
            ISSUE_TILE((kt + 1) * 64, Ksn, Ksn + 64 * KSW);
        }
        const unsigned long long mw0 = mrow0[kt];
        const unsigned long long mw1 = mrow1[kt];

        // ---- S^T = K (q/sqrtD)^T : D[m=key][n=q]; key = 16*cb+quad*4+reg, q = lane&15 ----
        f32x4 sacc[2][4];
        #pragma unroll
        for (int g = 0; g < 2; ++g)
            #pragma unroll
            for (int cb = 0; cb < 4; ++cb) sacc[g][cb] = (f32x4){0.f, 0.f, 0.f, 0.f};
        #pragma unroll
        for (int cb = 0; cb < 4; ++cb) {
            s16x8 kf[4];
            #pragma unroll
            for (int kc = 0; kc < 4; ++kc)
                kf[kc] = *(const s16x8*)&Ksc[(16 * cb + lrow) * KSW
                                             + ((kc * 32 + quad * 8) ^ ((lrow & 7) << 3))];
            #pragma unroll
            for (int g = 0; g < 2; ++g)
                #pragma unroll
                for (int kc = 0; kc < 4; ++kc)
                    sacc[g][cb] = MFMA32(kf[kc], qf[g][kc], sacc[g][cb]);
        }

        // ---- softmax (per-lane state, q=lane&15) + pf pack (sacc layout == MFMA16 B-operand!) ----
        s16x4 pf[2][4];
        #pragma unroll
        for (int g = 0; g < 2; ++g) {
            const unsigned long long mw = g ? mw1 : mw0;
            float sv[4][4];
            float tm = -INFINITY;
            #pragma unroll
            for (int cb = 0; cb < 4; ++cb) {
                unsigned nib = (unsigned)(mw >> (16 * cb + quad * 4)) & 0xFu;
                #pragma unroll
                for (int r = 0; r < 4; ++r) {
                    sv[cb][r] = (nib & (1u << r)) ? sacc[g][cb][r] : NEGF;
                    tm = fmaxf(tm, sv[cb][r]);
                }
            }
            tm = fmaxf(tm, __shfl_xor(tm, 16));
            tm = fmaxf(tm, __shfl_xor(tm, 32));
            float mn = fmaxf(m_run[g], tm);
            float al = __expf(m_run[g] - mn);
            float rs = 0.f;
            #pragma unroll
            for (int cb = 0; cb < 4; ++cb) {
                float p0 = __expf(sv[cb][0] - mn);
                float p1 = __expf(sv[cb][1] - mn);
                float p2 = __expf(sv[cb][2] - mn);
                float p3 = __expf(sv[cb][3] - mn);
                rs += (p0 + p1) + (p2 + p3);
                s16x4 pk;
                pk[0] = (short)f2bf(p0); pk[1] = (short)f2bf(p1);
                pk[2] = (short)f2bf(p2); pk[3] = (short)f2bf(p3);
                pf[g][cb] = pk;
            }
            rs += __shfl_xor(rs, 16);
            rs += __shfl_xor(rs, 32);
            l_run[g] = l_run[g] * al + rs;
            m_run[g] = mn;
            // O^T rescale: q = lane&15 -> per-lane al applies directly, no transpose
            #pragma unroll
            for (int nb = 0; nb < 8; ++nb)
                #pragma unroll
                for (int r = 0; r < 4; ++r) oacc[g][nb][r] *= al;
        }

        // ---- O^T += V^T P^T : MFMA16, A = V^T frag (LDS, swizzled read), B = pf (registers) ----
        #pragma unroll
        for (int nb = 0; nb < 8; ++nb) {
            #pragma unroll
            for (int kb = 0; kb < 4; ++kb) {
                s16x4 vf = *(const s16x4*)&Vtc[(16 * nb + lrow) * VSW
                                               + ((kb * 16 + quad * 4) ^ ((lrow & 7) << 3))];
                #pragma unroll
                for (int g = 0; g < 2; ++g)
                    oacc[g][nb] = MFMA16(vf, pf[g][kb], oacc[g][nb]);
            }
        }
    }
    #undef ISSUE_TILE

    // ---- fused out-projection: out = (O/l) Wo^T + bo ----
    __syncthreads();
    const float* wbase = wo + (size_t)h * Dh * Dh;
    #pragma unroll
    for (int p = 0; p < 16; ++p) {
        int slot = p * 256 + tid;
        int r = slot >> 5, c4 = (slot & 31) << 2;
        float4 wv = *(const float4*)(wbase + (size_t)r * Dh + c4);
        ushort4 pb;
        pb.x = f2bf(wv.x); pb.y = f2bf(wv.y); pb.z = f2bf(wv.z); pb.w = f2bf(wv.w);
        *(ushort4*)&Ws[r * WS_LD + c4] = pb;
    }
    // per-wave: normalized O^T -> Osl[q][d] (b64 writes, q=lrow rows), reread as A-frags [m=q][k=d]
    s16x8 afo[2][4];
    #pragma unroll
    for (int g = 0; g < 2; ++g) {
        float inv = 1.0f / l_run[g];   // per-lane, q = lane&15: no shuffle needed
        #pragma unroll
        for (int nb = 0; nb < 8; ++nb) {
            ushort4 pk;
            pk.x = f2bf(oacc[g][nb][0] * inv);
            pk.y = f2bf(oacc[g][nb][1] * inv);
            pk.z = f2bf(oacc[g][nb][2] * inv);
            pk.w = f2bf(oacc[g][nb][3] * inv);
            *(ushort4*)&Osl[lrow * OS_LD + 16 * nb + quad * 4] = pk;
        }
        #pragma unroll
        for (int kc = 0; kc < 4; ++kc)
            afo[g][kc] = *(const s16x8*)&Osl[lrow * OS_LD + kc * 32 + quad * 8];
    }
    __syncthreads();

    const size_t orow0 = (size_t)b * SS + s0 + 32 * wave;
    #pragma unroll
    for (int nb = 0; nb < 8; ++nb) {
        float bia = bo[h * Dh + nb * 16 + lrow];
        f32x4 facc[2];
        facc[0] = (f32x4){0.f, 0.f, 0.f, 0.f};
        facc[1] = (f32x4){0.f, 0.f, 0.f, 0.f};
        #pragma unroll
        for (int kc = 0; kc < 4; ++kc) {
            s16x8 wf = *(const s16x8*)&Ws[(16 * nb + lrow) * WS_LD + kc * 32 + quad * 8];
            facc[0] = MFMA32(afo[0][kc], wf, facc[0]);
            facc[1] = MFMA32(afo[1][kc], wf, facc[1]);
        }
        #pragma unroll
        for (int g = 0; g < 2; ++g)
            #pragma unroll
            for (int reg = 0; reg < 4; ++reg) {
                size_t m = orow0 + 16 * g + quad * 4 + reg;
                out[m * (NH * Dh) + h * Dh + nb * 16 + lrow] = facc[g][reg] + bia;
            }
    }
}

extern "C" void kernel_launch(void* const* d_in, const int* in_sizes, int n_in,
                              void* d_out, int out_size, void* d_ws, size_t ws_size,
                              hipStream_t stream) {
    const float* x     = (const float*)d_in[0];
    const int*   edge  = (const int*)d_in[1];
    const float* w_in  = (const float*)d_in[2];
    const float* b_in  = (const float*)d_in[3];
    const float* w_out = (const float*)d_in[4];
    const float* b_out = (const float*)d_in[5];
    float* out = (float*)d_out;

    float* ws   = (float*)d_ws;
    float* part = ws;                                              // 512 floats (reserve 1024)
    unsigned long long* mbit = (unsigned long long*)(ws + 1024);   // [4][1024][16] u64 = 512 KB
    ushort* qo  = (ushort*)(mbit + (size_t)NH * SS * 16);
    const size_t QSZ = (size_t)NB * NH * SS * 128;
    ushort* ko  = qo + QSZ;
    ushort* vto = ko + QSZ;                                        // [b][h][128][s]
    ushort* wb  = vto + QSZ;                                       // [1536][128] bf16 W_in

    ln_mask_kernel<<<256, 256, 0, stream>>>(x, part, edge, mbit, w_in, wb);
    qkv_mfma_kernel<<<dim3(12, 128), 256, 0, stream>>>(x, part, wb, b_in, qo, ko, vto);
    attn_fused_kernel<<<dim3(NB * NH, SS / 128), 256, 0, stream>>>(qo, ko, vto, mbit, w_out, b_out, out);
}

// Round 14
// 159.667 us; speedup vs baseline: 1.1155x; 1.1155x over previous
//
#include <hip/hip_runtime.h>
#include <math.h>

static constexpr int Dh = 128;
static constexpr int NH = 4;
static constexpr int NB = 16;
static constexpr int SS = 1024;
static constexpr float NEGF = -1e9f;
static constexpr float SCALE = 0.08838834764831843f;  // 1/sqrt(128)

typedef short s16x8 __attribute__((ext_vector_type(8)));
typedef short s16x4 __attribute__((ext_vector_type(4)));
typedef float f32x4 __attribute__((ext_vector_type(4)));

#define MFMA32(a, b, c) __builtin_amdgcn_mfma_f32_16x16x32_bf16(a, b, c, 0, 0, 0)
// K=16 bf16 MFMA: layouts HW-validated (byte-identical absmax across rounds).
#define MFMA16(a, b, c) __builtin_amdgcn_mfma_f32_16x16x16bf16_1k(a, b, c, 0, 0, 0)

// async global->LDS, 16B per lane; LDS dest is wave-uniform base + lane*16 (linear),
// per-lane GLOBAL address carries the swizzle (m173 pattern, HW-validated in R10).
#define GL2LDS16(g, l)                                                                   \
    __builtin_amdgcn_global_load_lds((const __attribute__((address_space(1))) void*)(g), \
                                     (__attribute__((address_space(3))) void*)(l), 16, 0, 0)

__device__ inline ushort f2bf(float f) {
    union { float f; unsigned u; } v; v.f = f;
    unsigned r = v.u + 0x7FFFu + ((v.u >> 16) & 1u);
    return (ushort)(r >> 16);
}

// ---------------- K0: LN partial sums + bit-mask prep + W_in bf16 pre-convert ----------------
__global__ __launch_bounds__(256) void ln_mask_kernel(const float* __restrict__ x,
                                                      float* __restrict__ part,
                                                      const int* __restrict__ edge,
                                                      unsigned long long* __restrict__ mbit,
                                                      const float* __restrict__ w_in,
                                                      ushort* __restrict__ wb) {
    const int b = blockIdx.x >> 4, p = blockIdx.x & 15;
    const int tid = threadIdx.x;
    const float4* xb4 = (const float4*)(x + (size_t)b * SS * Dh) + p * 2048;
    float s = 0.f, ss = 0.f;
    for (int i = tid; i < 2048; i += 256) {
        float4 v = xb4[i];
        s  += v.x + v.y + v.z + v.w;
        ss += v.x * v.x + v.y * v.y + v.z * v.z + v.w * v.w;
    }
    __shared__ float r1[256], r2[256];
    r1[tid] = s; r2[tid] = ss;
    __syncthreads();
    for (int off = 128; off > 0; off >>= 1) {
        if (tid < off) { r1[tid] += r1[tid + off]; r2[tid] += r2[tid + off]; }
        __syncthreads();
    }
    if (tid == 0) { part[blockIdx.x * 2] = r1[0]; part[blockIdx.x * 2 + 1] = r2[0]; }

    if (blockIdx.x < 64) {
        const int idx = blockIdx.x * 256 + tid;   // < 1024*16
        const int sr = idx >> 4, w = idx & 15;
        const int4* ep = (const int4*)(edge + (size_t)sr * SS + w * 64);
        unsigned long long m0 = 0, m1 = 0, m2 = 0, m3 = 0;
        #pragma unroll
        for (int j = 0; j < 16; ++j) {
            int4 e = ep[j];
            const int base = j * 4;
            m0 |= (e.x == 1) ? (1ull << (base + 0)) : 0ull;
            m1 |= (e.x == 2) ? (1ull << (base + 0)) : 0ull;
            m2 |= (e.x == 3) ? (1ull << (base + 0)) : 0ull;
            m3 |= (e.x == 4) ? (1ull << (base + 0)) : 0ull;
            m0 |= (e.y == 1) ? (1ull << (base + 1)) : 0ull;
            m1 |= (e.y == 2) ? (1ull << (base + 1)) : 0ull;
            m2 |= (e.y == 3) ? (1ull << (base + 1)) : 0ull;
            m3 |= (e.y == 4) ? (1ull << (base + 1)) : 0ull;
            m0 |= (e.z == 1) ? (1ull << (base + 2)) : 0ull;
            m1 |= (e.z == 2) ? (1ull << (base + 2)) : 0ull;
            m2 |= (e.z == 3) ? (1ull << (base + 2)) : 0ull;
            m3 |= (e.z == 4) ? (1ull << (base + 2)) : 0ull;
            m0 |= (e.w == 1) ? (1ull << (base + 3)) : 0ull;
            m1 |= (e.w == 2) ? (1ull << (base + 3)) : 0ull;
            m2 |= (e.w == 3) ? (1ull << (base + 3)) : 0ull;
            m3 |= (e.w == 4) ? (1ull << (base + 3)) : 0ull;
        }
        mbit[((size_t)0 * SS + sr) * 16 + w] = m0;
        mbit[((size_t)1 * SS + sr) * 16 + w] = m1;
        mbit[((size_t)2 * SS + sr) * 16 + w] = m2;
        mbit[((size_t)3 * SS + sr) * 16 + w] = m3;
    } else if (blockIdx.x < 160) {
        // W_in -> bf16 : 1536*128 elems; 96 blocks x 256 threads x 8
        const int slot = (blockIdx.x - 64) * 256 + tid;
        const float4* sp = (const float4*)w_in + (size_t)slot * 2;
        float4 a = sp[0], c = sp[1];
        s16x8 pk;
        pk[0] = (short)f2bf(a.x); pk[1] = (short)f2bf(a.y);
        pk[2] = (short)f2bf(a.z); pk[3] = (short)f2bf(a.w);
        pk[4] = (short)f2bf(c.x); pk[5] = (short)f2bf(c.y);
        pk[6] = (short)f2bf(c.z); pk[7] = (short)f2bf(c.w);
        *(s16x8*)(wb + (size_t)slot * 8) = pk;
    }
}

// ---------------- K0.5: xn = LN(x) -> bf16 ----------------
__global__ __launch_bounds__(256) void xcast_kernel(const float* __restrict__ x,
                                                    const float* __restrict__ part,
                                                    ushort* __restrict__ xb) {
    const int b = blockIdx.x >> 6;
    float s = 0.f, ss = 0.f;
    #pragma unroll
    for (int p = 0; p < 16; ++p) { s += part[(b * 16 + p) * 2]; ss += part[(b * 16 + p) * 2 + 1]; }
    const float invN = 1.0f / (float)(SS * Dh);
    const float mu = s * invN;
    const float rstd = 1.0f / sqrtf(ss * invN - mu * mu + 1e-5f);
    const size_t base = ((size_t)blockIdx.x * 256 + threadIdx.x) * 8;
    float4 v0 = *(const float4*)(x + base);
    float4 v1 = *(const float4*)(x + base + 4);
    s16x8 pk;
    pk[0] = (short)f2bf((v0.x - mu) * rstd); pk[1] = (short)f2bf((v0.y - mu) * rstd);
    pk[2] = (short)f2bf((v0.z - mu) * rstd); pk[3] = (short)f2bf((v0.w - mu) * rstd);
    pk[4] = (short)f2bf((v1.x - mu) * rstd); pk[5] = (short)f2bf((v1.y - mu) * rstd);
    pk[6] = (short)f2bf((v1.z - mu) * rstd); pk[7] = (short)f2bf((v1.w - mu) * rstd);
    *(s16x8*)(xb + base) = pk;
}

// ---------------- K1: QKV projection with async gload_lds staging.
// K=128 fits entirely in LDS: issue ALL 16 async loads upfront (A/B x 2 K-halves, 64 KB),
// ONE barrier for the whole main phase, zero ds_writes, zero staging registers.
// Linear LDS dest + inverse-swizzled global source + XOR-swizzled reads (R10-proven).
// Epilogue unchanged (Rs[128][136] aliases the staging buffers). ----------------
static constexpr int QKV_HALF = 128 * 64;   // ushorts per operand-half buffer (16 KB)

__global__ __launch_bounds__(256) void qkv_mfma_kernel(const ushort* __restrict__ xb,   // [16384][128] bf16 LN'd
                                                       const ushort* __restrict__ wb,   // [1536][128] bf16
                                                       const float* __restrict__ bias,  // [1536]
                                                       ushort* __restrict__ qo,
                                                       ushort* __restrict__ ko,
                                                       ushort* __restrict__ vto) {
    __shared__ ushort smem[4 * QKV_HALF];     // A0,B0,A1,B1 = 64 KB; epilogue alias Rs[128][136]
    ushort* Rs = smem;
    const int tid = threadIdx.x, wave = tid >> 6, lane = tid & 63;
    const int lrow = lane & 15, quad = lane >> 4;
    const int wm = wave & 1, wn = wave >> 1;
    const int col0 = blockIdx.x * 128;
    const int row0 = blockIdx.y * 128;
    const int bb = row0 >> 10;

    // issue all staging upfront: rows 128, 8 chunks of 16B per row; src col pre-swizzled
    #pragma unroll
    for (int h2 = 0; h2 < 2; ++h2) {
        ushort* Ad = smem + (2 * h2) * QKV_HALF;
        ushort* Bd = smem + (2 * h2 + 1) * QKV_HALF;
        const int kk = h2 * 64;
        #pragma unroll
        for (int p = 0; p < 4; ++p) {
            const int r = p * 32 + wave * 8 + (lane >> 3);
            const int sc = ((lane & 7) * 8) ^ ((r & 7) << 3);
            GL2LDS16(xb + (size_t)(row0 + r) * Dh + kk + sc, Ad + (p * 32 + wave * 8) * 64);
            GL2LDS16(wb + (size_t)(col0 + r) * Dh + kk + sc, Bd + (p * 32 + wave * 8) * 64);
        }
    }

    f32x4 acc[4][4];
    #pragma unroll
    for (int mi = 0; mi < 4; ++mi)
        #pragma unroll
        for (int ni = 0; ni < 4; ++ni) acc[mi][ni] = (f32x4){0.f, 0.f, 0.f, 0.f};

    __syncthreads();   // drains vmcnt: both K-halves resident; only barrier of the main phase

    #pragma unroll
    for (int h2 = 0; h2 < 2; ++h2) {
        const ushort* As = smem + (2 * h2) * QKV_HALF;
        const ushort* Bs = smem + (2 * h2 + 1) * QKV_HALF;
        #pragma unroll
        for (int kc = 0; kc < 2; ++kc) {
            const int cs = (kc * 32 + quad * 8) ^ ((lrow & 7) << 3);
            s16x8 af[4], bf[4];
            #pragma unroll
            for (int mi = 0; mi < 4; ++mi)
                af[mi] = *(const s16x8*)&As[(wm * 64 + 16 * mi + lrow) * 64 + cs];
            #pragma unroll
            for (int ni = 0; ni < 4; ++ni)
                bf[ni] = *(const s16x8*)&Bs[(wn * 64 + 16 * ni + lrow) * 64 + cs];
            #pragma unroll
            for (int mi = 0; mi < 4; ++mi)
                #pragma unroll
                for (int ni = 0; ni < 4; ++ni)
                    acc[mi][ni] = MFMA32(af[mi], bf[ni], acc[mi][ni]);
        }
    }

    const int seg = col0 % 384, typ = seg >> 7, h = col0 / 384;
    const size_t bh = (size_t)bb * NH + h;
    const int sl_blk = row0 & 1023;
    float bia[4];
    #pragma unroll
    for (int ni = 0; ni < 4; ++ni) bia[ni] = bias[col0 + wn * 64 + 16 * ni + lrow];
    const float sc = (typ == 0) ? SCALE : 1.f;

    __syncthreads();
    if (typ < 2) {
        #pragma unroll
        for (int mi = 0; mi < 4; ++mi)
            #pragma unroll
            for (int ni = 0; ni < 4; ++ni)
                #pragma unroll
                for (int reg = 0; reg < 4; ++reg)
                    Rs[(wm * 64 + 16 * mi + quad * 4 + reg) * 136 + wn * 64 + 16 * ni + lrow]
                        = f2bf((acc[mi][ni][reg] + bia[ni]) * sc);
    } else {
        #pragma unroll
        for (int mi = 0; mi < 4; ++mi)
            #pragma unroll
            for (int ni = 0; ni < 4; ++ni) {
                ushort4 pk;
                pk.x = f2bf(acc[mi][ni][0] + bia[ni]);
                pk.y = f2bf(acc[mi][ni][1] + bia[ni]);
                pk.z = f2bf(acc[mi][ni][2] + bia[ni]);
                pk.w = f2bf(acc[mi][ni][3] + bia[ni]);
                *(ushort4*)&Rs[(wn * 64 + 16 * ni + lrow) * 136 + wm * 64 + 16 * mi + quad * 4] = pk;
            }
    }
    __syncthreads();

    ushort* dstb;
    int pitch;
    if (typ == 0)      { dstb = qo  + bh * SS * 128 + (size_t)sl_blk * 128; pitch = 128; }
    else if (typ == 1) { dstb = ko  + bh * SS * 128 + (size_t)sl_blk * 128; pitch = 128; }
    else               { dstb = vto + bh * (size_t)128 * SS + sl_blk;       pitch = SS;  }
    #pragma unroll
    for (int p = 0; p < 8; ++p) {
        int slot = p * 256 + tid;
        int r = slot >> 4, c8 = (slot & 15) * 8;
        *(s16x8*)&dstb[(size_t)r * pitch + c8] = *(const s16x8*)&Rs[r * 136 + c8];
    }
}

// ---------------- K2: R10 flash attention (async gload_lds staging, best-measured) ----------------
static constexpr int KSW = 128;                      // Ks row stride (linear, content swizzled)
static constexpr int VSW = 64;                       // Vt row stride
static constexpr int TILE_U = 64 * KSW + 128 * VSW;  // 16384 ushorts per buffer
static constexpr int WS_LD = 136;
static constexpr int OS_LD = 136;

__global__ __launch_bounds__(256, 2) void attn_fused_kernel(const ushort* __restrict__ qg_,
                                                            const ushort* __restrict__ kg_,
                                                            const ushort* __restrict__ vg_,
                                                            const unsigned long long* __restrict__ mbit,
                                                            const float* __restrict__ wo,
                                                            const float* __restrict__ bo,
                                                            float* __restrict__ out) {
    // XCD swizzle: blockIdx.x = (b,h) so all 8 q-tiles of a (b,h) share id%8 -> same XCD L2
    const int bhi = blockIdx.x, qt = blockIdx.y;
    const int b = bhi >> 2, h = bhi & 3;
    const int s0 = qt * 128;
    const int tid = threadIdx.x;
    const int wave = tid >> 6, lane = tid & 63;
    const int lrow = lane & 15, quad = lane >> 4;

    __shared__ ushort smem[2 * TILE_U];          // 65536 B exactly
    ushort* Osl = smem + wave * 16 * OS_LD;      // epilogue: per-wave [q][d], aliases buffers
    ushort* Ws  = smem + 4 * 16 * OS_LD;         // epilogue: Wo[h] bf16 [e][d]

    const size_t bh = (size_t)(b * NH + h);
    const ushort* qg = qg_ + bh * SS * 128;
    const ushort* kg = kg_ + bh * SS * 128;
    const ushort* vg = vg_ + bh * 128 * SS;
    const unsigned long long* mrow0 = mbit + ((size_t)h * SS + (s0 + 32 * wave + lrow)) * 16;
    const unsigned long long* mrow1 = mrow0 + 16 * 16;

    // Q fragments (B-operand of S^T MFMA32): n=q=lane&15, k=kc*32+quad*8+j
    s16x8 qf[2][4];
    #pragma unroll
    for (int g = 0; g < 2; ++g) {
        const ushort* qr = qg + (size_t)(s0 + 32 * wave + 16 * g + lrow) * 128 + quad * 8;
        #pragma unroll
        for (int kc = 0; kc < 4; ++kc) qf[g][kc] = *(const s16x8*)(qr + kc * 32);
    }

    // per-lane swizzled source offsets (constant across tiles):
    // K: lds row rk (4 rows/call), chunk (lane&15); src col = ((lane&15)*8) ^ ((rk&7)<<3)
    // V: lds row rv (8 rows/call), chunk (lane&7);  src col = ((lane&7)*8) ^ ((rv&7)<<3)
    #define ISSUE_TILE(T0, KD, VD)                                                            \
        {                                                                                     \
            _Pragma("unroll")                                                                 \
            for (int p = 0; p < 4; ++p) {                                                     \
                const int rk = wave * 16 + p * 4 + (lane >> 4);                               \
                GL2LDS16(kg + (size_t)((T0) + rk) * 128 + (((lane & 15) * 8) ^ ((rk & 7) << 3)), \
                         (KD) + (wave * 16 + p * 4) * KSW);                                   \
                const int rv = wave * 32 + p * 8 + (lane >> 3);                               \
                GL2LDS16(vg + (size_t)rv * SS + (T0) + (((lane & 7) * 8) ^ ((rv & 7) << 3)),  \
                         (VD) + (wave * 32 + p * 8) * VSW);                                   \
            }                                                                                 \
        }

    // prologue: issue tile 0 into buffer 0
    ISSUE_TILE(0, smem, smem + 64 * KSW);

    // O^T accumulators: D[m=d][n=q]: q = lane&15 (aligned with softmax state!), d = 16*nb+quad*4+reg
    f32x4 oacc[2][8];
    #pragma unroll
    for (int g = 0; g < 2; ++g)
        #pragma unroll
        for (int nb = 0; nb < 8; ++nb) oacc[g][nb] = (f32x4){0.f, 0.f, 0.f, 0.f};
    float m_run[2] = {-INFINITY, -INFINITY};
    float l_run[2] = {0.f, 0.f};

    for (int kt = 0; kt < 16; ++kt) {
        const ushort* Ksc = smem + (kt & 1) * TILE_U;
        const ushort* Vtc = Ksc + 64 * KSW;

        __syncthreads();   // drains vmcnt: tile kt resident in buf[kt&1]; all waves aligned

        if (kt < 15) {
            ushort* Ksn = smem + ((kt + 1) & 1) * TILE_U;
            ISSUE_TILE((kt + 1) * 64, Ksn, Ksn + 64 * KSW);
        }
        const unsigned long long mw0 = mrow0[kt];
        const unsigned long long mw1 = mrow1[kt];

        // ---- S^T = K (q/sqrtD)^T : D[m=key][n=q]; key = 16*cb+quad*4+reg, q = lane&15 ----
        f32x4 sacc[2][4];
        #pragma unroll
        for (int g = 0; g < 2; ++g)
            #pragma unroll
            for (int cb = 0; cb < 4; ++cb) sacc[g][cb] = (f32x4){0.f, 0.f, 0.f, 0.f};
        #pragma unroll
        for (int cb = 0; cb < 4; ++cb) {
            s16x8 kf[4];
            #pragma unroll
            for (int kc = 0; kc < 4; ++kc)
                kf[kc] = *(const s16x8*)&Ksc[(16 * cb + lrow) * KSW
                                             + ((kc * 32 + quad * 8) ^ ((lrow & 7) << 3))];
            #pragma unroll
            for (int g = 0; g < 2; ++g)
                #pragma unroll
                for (int kc = 0; kc < 4; ++kc)
                    sacc[g][cb] = MFMA32(kf[kc], qf[g][kc], sacc[g][cb]);
        }

        // ---- softmax (per-lane state, q=lane&15) + pf pack (sacc layout == MFMA16 B-operand!) ----
        s16x4 pf[2][4];
        #pragma unroll
        for (int g = 0; g < 2; ++g) {
            const unsigned long long mw = g ? mw1 : mw0;
            float sv[4][4];
            float tm = -INFINITY;
            #pragma unroll
            for (int cb = 0; cb < 4; ++cb) {
                unsigned nib = (unsigned)(mw >> (16 * cb + quad * 4)) & 0xFu;
                #pragma unroll
                for (int r = 0; r < 4; ++r) {
                    sv[cb][r] = (nib & (1u << r)) ? sacc[g][cb][r] : NEGF;
                    tm = fmaxf(tm, sv[cb][r]);
                }
            }
            tm = fmaxf(tm, __shfl_xor(tm, 16));
            tm = fmaxf(tm, __shfl_xor(tm, 32));
            float mn = fmaxf(m_run[g], tm);
            float al = __expf(m_run[g] - mn);
            float rs = 0.f;
            #pragma unroll
            for (int cb = 0; cb < 4; ++cb) {
                float p0 = __expf(sv[cb][0] - mn);
                float p1 = __expf(sv[cb][1] - mn);
                float p2 = __expf(sv[cb][2] - mn);
                float p3 = __expf(sv[cb][3] - mn);
                rs += (p0 + p1) + (p2 + p3);
                s16x4 pk;
                pk[0] = (short)f2bf(p0); pk[1] = (short)f2bf(p1);
                pk[2] = (short)f2bf(p2); pk[3] = (short)f2bf(p3);
                pf[g][cb] = pk;
            }
            rs += __shfl_xor(rs, 16);
            rs += __shfl_xor(rs, 32);
            l_run[g] = l_run[g] * al + rs;
            m_run[g] = mn;
            // O^T rescale: q = lane&15 -> per-lane al applies directly, no transpose
            #pragma unroll
            for (int nb = 0; nb < 8; ++nb)
                #pragma unroll
                for (int r = 0; r < 4; ++r) oacc[g][nb][r] *= al;
        }

        // ---- O^T += V^T P^T : MFMA16, A = V^T frag (LDS, swizzled read), B = pf (registers) ----
        #pragma unroll
        for (int nb = 0; nb < 8; ++nb) {
            #pragma unroll
            for (int kb = 0; kb < 4; ++kb) {
                s16x4 vf = *(const s16x4*)&Vtc[(16 * nb + lrow) * VSW
                                               + ((kb * 16 + quad * 4) ^ ((lrow & 7) << 3))];
                #pragma unroll
                for (int g = 0; g < 2; ++g)
                    oacc[g][nb] = MFMA16(vf, pf[g][kb], oacc[g][nb]);
            }
        }
    }
    #undef ISSUE_TILE

    // ---- fused out-projection: out = (O/l) Wo^T + bo ----
    __syncthreads();
    const float* wbase = wo + (size_t)h * Dh * Dh;
    #pragma unroll
    for (int p = 0; p < 16; ++p) {
        int slot = p * 256 + tid;
        int r = slot >> 5, c4 = (slot & 31) << 2;
        float4 wv = *(const float4*)(wbase + (size_t)r * Dh + c4);
        ushort4 pb;
        pb.x = f2bf(wv.x); pb.y = f2bf(wv.y); pb.z = f2bf(wv.z); pb.w = f2bf(wv.w);
        *(ushort4*)&Ws[r * WS_LD + c4] = pb;
    }
    // per-wave: normalized O^T -> Osl[q][d] (b64 writes, q=lrow rows), reread as A-frags [m=q][k=d]
    s16x8 afo[2][4];
    #pragma unroll
    for (int g = 0; g < 2; ++g) {
        float inv = 1.0f / l_run[g];   // per-lane, q = lane&15: no shuffle needed
        #pragma unroll
        for (int nb = 0; nb < 8; ++nb) {
            ushort4 pk;
            pk.x = f2bf(oacc[g][nb][0] * inv);
            pk.y = f2bf(oacc[g][nb][1] * inv);
            pk.z = f2bf(oacc[g][nb][2] * inv);
            pk.w = f2bf(oacc[g][nb][3] * inv);
            *(ushort4*)&Osl[lrow * OS_LD + 16 * nb + quad * 4] = pk;
        }
        #pragma unroll
        for (int kc = 0; kc < 4; ++kc)
            afo[g][kc] = *(const s16x8*)&Osl[lrow * OS_LD + kc * 32 + quad * 8];
    }
    __syncthreads();

    const size_t orow0 = (size_t)b * SS + s0 + 32 * wave;
    #pragma unroll
    for (int nb = 0; nb < 8; ++nb) {
        float bia = bo[h * Dh + nb * 16 + lrow];
        f32x4 facc[2];
        facc[0] = (f32x4){0.f, 0.f, 0.f, 0.f};
        facc[1] = (f32x4){0.f, 0.f, 0.f, 0.f};
        #pragma unroll
        for (int kc = 0; kc < 4; ++kc) {
            s16x8 wf = *(const s16x8*)&Ws[(16 * nb + lrow) * WS_LD + kc * 32 + quad * 8];
            facc[0] = MFMA32(afo[0][kc], wf, facc[0]);
            facc[1] = MFMA32(afo[1][kc], wf, facc[1]);
        }
        #pragma unroll
        for (int g = 0; g < 2; ++g)
            #pragma unroll
            for (int reg = 0; reg < 4; ++reg) {
                size_t m = orow0 + 16 * g + quad * 4 + reg;
                out[m * (NH * Dh) + h * Dh + nb * 16 + lrow] = facc[g][reg] + bia;
            }
    }
}

extern "C" void kernel_launch(void* const* d_in, const int* in_sizes, int n_in,
                              void* d_out, int out_size, void* d_ws, size_t ws_size,
                              hipStream_t stream) {
    const float* x     = (const float*)d_in[0];
    const int*   edge  = (const int*)d_in[1];
    const float* w_in  = (const float*)d_in[2];
    const float* b_in  = (const float*)d_in[3];
    const float* w_out = (const float*)d_in[4];
    const float* b_out = (const float*)d_in[5];
    float* out = (float*)d_out;

    float* ws   = (float*)d_ws;
    float* part = ws;                                              // 512 floats (reserve 1024)
    unsigned long long* mbit = (unsigned long long*)(ws + 1024);   // [4][1024][16] u64 = 512 KB
    ushort* qo  = (ushort*)(mbit + (size_t)NH * SS * 16);
    const size_t QSZ = (size_t)NB * NH * SS * 128;
    ushort* ko  = qo + QSZ;
    ushort* vto = ko + QSZ;                                        // [b][h][128][s]
    ushort* xb  = vto + QSZ;                                       // [16384][128] bf16 LN'd x (4 MB)
    ushort* wb  = xb + (size_t)NB * SS * Dh;                       // [1536][128] bf16 W_in

    ln_mask_kernel<<<256, 256, 0, stream>>>(x, part, edge, mbit, w_in, wb);
    xcast_kernel<<<1024, 256, 0, stream>>>(x, part, xb);
    qkv_mfma_kernel<<<dim3(12, 128), 256, 0, stream>>>(xb, wb, b_in, qo, ko, vto);
    attn_fused_kernel<<<dim3(NB * NH, SS / 128), 256, 0, stream>>>(qo, ko, vto, mbit, w_out, b_out, out);
}